// Round 1
// baseline (2356.930 us; speedup 1.0000x reference)
//
#include <hip/hip_runtime.h>
#include <hip/hip_fp16.h>

// MINE estimator, dropout analytically marginalized:
//   mean(z1)  -> no-dropout forward (exact expectation)
//   E[exp(z2)] = exp(b3) * prod_j (0.5 + 0.5*exp(2*a_j)),  a_j = w3_j*relu(h2_j)
//   permutation -> 20 fixed cyclic shifts (unbiased pairing estimator)
// R5: fc23 restructured to kill register spill + redundant P traffic.
//   - 512 threads / 8 waves, each wave owns a 32x80 output quadrant ->
//     acc[2][5] = 40 VGPRs (was acc[4][5] = 80 -> spilled ~1.85 GB/dispatch
//     of scratch writes, visible as WRITE_SIZE).
//   - p-loop (21 passes) moved inside the block: P tile held in registers
//     (5 x f16x8 per thread) across all passes -> P read once, not 21x.
//   - Q tile re-read per pass (shift-dependent, unavoidable); 2 barriers/pass.

#define N_SAMP  131072
#define NMASK   (N_SAMP - 1)
#define HH      300
#define HPAD    320
#define DD      256
#define KPASS   20
#define PSTRIDE 320

#define OFF_S    ((size_t)0)
#define OFF_B1P  ((size_t)1024)
#define OFF_B2P  ((size_t)2304)
#define OFF_W3P  ((size_t)3584)
#define OFF_C2   ((size_t)4864)
#define OFF_W1B  ((size_t)8192)                       // [20 nt][8 kt][64 lane][8] f16
#define OFF_W2B  (OFF_W1B + (size_t)163840)           // [20 nt][10 kt][64 lane][8] f16
#define OFF_P    (OFF_W2B + (size_t)204800)
#define OFF_Q    (OFF_P + (size_t)N_SAMP*PSTRIDE*2)

typedef _Float16 f16x8 __attribute__((ext_vector_type(8)));
typedef float    fx4   __attribute__((ext_vector_type(4)));

__global__ void prep_kernel(const float* __restrict__ W1, const float* __restrict__ b1,
                            const float* __restrict__ W2, const float* __restrict__ b2,
                            const float* __restrict__ W3, char* __restrict__ ws)
{
    double* S     = (double*)(ws + OFF_S);
    float* b1p    = (float*)(ws + OFF_B1P);
    float* b2p    = (float*)(ws + OFF_B2P);
    float* w3p    = (float*)(ws + OFF_W3P);
    float* c2p    = (float*)(ws + OFF_C2);
    _Float16* w1b = (_Float16*)(ws + OFF_W1B);
    _Float16* w2b = (_Float16*)(ws + OFF_W2B);
    int tid = blockIdx.x * blockDim.x + threadIdx.x;
    int nth = gridDim.x * blockDim.x;
    if (tid <= KPASS) S[tid] = 0.0;
    for (int i = tid; i < HPAD; i += nth) {
        b1p[i] = (i < HH) ? b1[i] : 0.f;
        b2p[i] = (i < HH) ? b2[i] : 0.f;
        w3p[i] = (i < HH) ? W3[i] : 0.f;
        c2p[i] = (i < HH) ? 2.8853900817779268f * W3[i] : 0.f;  // 2*log2(e)*w3
    }
    // w1b: frag (nt,kt): value = W1[n][k], n = nt*16+tx, k = kt*32+quad*8+j (K=256)
    for (int i = tid; i < 20 * 8 * 64 * 8; i += nth) {
        const int j = i & 7, lane = (i >> 3) & 63, rem = i >> 9;
        const int kt = rem & 7, nt = rem >> 3;
        const int n = nt * 16 + (lane & 15);
        const int k = kt * 32 + (lane >> 4) * 8 + j;
        w1b[i] = (n < HH) ? (_Float16)W1[n * DD + k] : (_Float16)0.f;
    }
    // w2b: frag (nt,kt): value = W2[n][k]; row k==300 carries b2 (bias fold)
    for (int i = tid; i < 20 * 10 * 64 * 8; i += nth) {
        const int j = i & 7, lane = (i >> 3) & 63, rem = i >> 9;
        const int kt = rem % 10, nt = rem / 10;
        const int n = nt * 16 + (lane & 15);
        const int k = kt * 32 + (lane >> 4) * 8 + j;
        float v = 0.f;
        if (n < HH) {
            if (k < HH)       v = W2[n * HH + k];
            else if (k == HH) v = b2[n];
        }
        w2b[i] = (_Float16)v;
    }
}

// fc1 on MFMA: gather x rows -> fp16 A-frags in LDS; P = u*W1a^T + b1 (kt 0..3),
// Q = v*W1b^T (kt 4..7). Epilogue transposes through LDS for coalesced stores.
__global__ __launch_bounds__(256, 2)
void fc1_kernel(const float* __restrict__ x, const int* __restrict__ ind,
                char* __restrict__ ws)
{
    const _Float16* w1b = (const _Float16*)(ws + OFF_W1B);
    const float* b1p    = (const float*)(ws + OFF_B1P);
    const int i0 = blockIdx.x * 128;

    __shared__ __align__(16) char lds[65536];   // At [8 kt][8 mt][64 slot][8] f16
    _Float16* At  = (_Float16*)lds;
    _Float16* buf = (_Float16*)lds;

    const int t    = threadIdx.x;
    const int lane = t & 63, w = t >> 6;
    const int tx   = lane & 15, quad = lane >> 4;
    const int colw = w * 80;

    {
        const int m = t >> 1, c = t & 1;
        const int mt = m >> 4, ml = m & 15;
        const int r = ind[i0 + m];
        const float* xr = x + (size_t)r * DD;
        #pragma unroll
        for (int i = 0; i < 16; ++i) {
            const int ch = 2 * i + c;
            const int kt = ch >> 2, qd = ch & 3;
            const float4 f0 = *(const float4*)(xr + ch * 8);
            const float4 f1 = *(const float4*)(xr + ch * 8 + 4);
            f16x8 h;
            h[0] = (_Float16)f0.x; h[1] = (_Float16)f0.y;
            h[2] = (_Float16)f0.z; h[3] = (_Float16)f0.w;
            h[4] = (_Float16)f1.x; h[5] = (_Float16)f1.y;
            h[6] = (_Float16)f1.z; h[7] = (_Float16)f1.w;
            *(f16x8*)(At + ((size_t)(kt * 8 + mt) * 64 + ml * 4 + qd) * 8) = h;
        }
    }
    __syncthreads();

    #pragma unroll
    for (int ph = 0; ph < 2; ++ph) {
        fx4 acc[8][5] = {};
        #pragma unroll
        for (int kt = 0; kt < 4; ++kt) {
            const int ktg = ph * 4 + kt;
            f16x8 bf[5];
            #pragma unroll
            for (int n = 0; n < 5; ++n)
                bf[n] = *(const f16x8*)(w1b + ((size_t)((w * 5 + n) * 8 + ktg) * 64 + lane) * 8);
            #pragma unroll
            for (int mh = 0; mh < 2; ++mh) {
                f16x8 af[4];
                #pragma unroll
                for (int mi = 0; mi < 4; ++mi)
                    af[mi] = *(const f16x8*)(At + ((size_t)(ktg * 8 + mh * 4 + mi) * 64 + tx * 4 + quad) * 8);
                #pragma unroll
                for (int mi = 0; mi < 4; ++mi)
                    #pragma unroll
                    for (int n = 0; n < 5; ++n)
                        acc[mh * 4 + mi][n] =
                            __builtin_amdgcn_mfma_f32_16x16x32_f16(af[mi], bf[n], acc[mh * 4 + mi][n], 0, 0, 0);
            }
        }
        _Float16* out = (_Float16*)(ws + (ph ? OFF_Q : OFF_P));
        #pragma unroll
        for (int g = 0; g < 4; ++g) {
            __syncthreads();
            #pragma unroll
            for (int mi = 0; mi < 2; ++mi) {
                const int mt = g * 2 + mi;
                #pragma unroll
                for (int n = 0; n < 5; ++n) {
                    const int col = colw + n * 16 + tx;
                    const float bb = (ph == 0) ? b1p[col] : 0.f;
                    #pragma unroll
                    for (int r = 0; r < 4; ++r) {
                        const int row32 = mi * 16 + quad * 4 + r;
                        buf[row32 * 328 + col] = (_Float16)(acc[mt][n][r] + bb);
                    }
                }
            }
            __syncthreads();
            #pragma unroll
            for (int s5 = 0; s5 < 5; ++s5) {
                const int idx = t + s5 * 256;
                const int rr = idx / 40, cc = idx - rr * 40;
                *(uint4*)(out + (size_t)(i0 + g * 32 + rr) * PSTRIDE + cc * 8) =
                    *(const uint4*)(buf + rr * 328 + cc * 8);
            }
        }
        __syncthreads();
    }
}

// fc2+fc3: h1 = relu(P_i + Q_{(i+shift)&mask}) [col 300 = 1 -> b2 fold];
// h2 = h1*W2b^T; epilogue in exp2/log2 domain.
// R5 structure: M=64 tile, 8 waves as (mh 0..1) x (nq 0..3); wave quadrant
// 32 rows x 80 cols -> acc[2][5] (40 regs, no spill). p-loop inside block:
// P chunks live in registers across all 21 passes.
__global__ __launch_bounds__(512, 4)
void fc23_kernel(char* __restrict__ ws)
{
    const _Float16* w2b = (const _Float16*)(ws + OFF_W2B);
    const float* w3p = (const float*)(ws + OFF_W3P);
    const float* c2p = (const float*)(ws + OFF_C2);
    const _Float16* P = (const _Float16*)(ws + OFF_P);
    const _Float16* Q = (const _Float16*)(ws + OFF_Q);
    double* S = (double*)(ws + OFF_S);

    const int i0 = blockIdx.x * 64;

    __shared__ __align__(16) char lds[40960 + 1024];
    _Float16* At = (_Float16*)lds;              // [4 mt][10 kt][64 slot][8] f16
    float* part = (float*)(lds + 40960);        // [64 rows][4 nq]

    const int t    = threadIdx.x;
    const int lane = t & 63, w = t >> 6;
    const int tx   = lane & 15, quad = lane >> 4;
    const int mh   = w >> 2, nq = w & 3;
    const int colw = nq * 80;

    // staging role: 8 threads per row, 5 chunks each (ch = sc + 8i)
    const int sc = t & 7, sm = t >> 3;
    const int smt = sm >> 4, sml = sm & 15;
    const int prow = i0 + sm;

    // P chunks held in registers across the whole p loop (read P ONCE)
    f16x8 pc[5];
    {
        const _Float16* pr = P + (size_t)prow * PSTRIDE;
        #pragma unroll
        for (int i = 0; i < 5; ++i)
            pc[i] = *(const f16x8*)(pr + (sc + 8 * i) * 8);
    }

    const _Float16* wb = w2b + (size_t)(nq * 5) * 10 * 512 + (size_t)lane * 8;

    for (int p = 0; p <= KPASS; ++p) {
        const unsigned shift = (p == 0) ? 0u : (((unsigned)p * 2654435761u) & NMASK);

        { // stage h1 = relu(P+Q) into fragment-layout LDS; col 300 -> 1.0
            const _Float16* qr = Q + (size_t)(((unsigned)prow + shift) & NMASK) * PSTRIDE;
            #pragma unroll
            for (int i = 0; i < 5; ++i) {
                const int ch = sc + 8 * i;
                f16x8 hq = *(const f16x8*)(qr + ch * 8);
                f16x8 sv = pc[i] + hq;
                sv = __builtin_elementwise_max(sv, (f16x8)(_Float16)0);
                if (ch == 37) sv[4] = (_Float16)1.f;   // k=300: bias column
                const int kt = ch >> 2, cq = ch & 3;
                *(f16x8*)(At + ((size_t)(smt * 10 + kt) * 64 + sml * 4 + cq) * 8) = sv;
            }
        }
        __syncthreads();   // At ready; prior part reads complete

        fx4 acc[2][5] = {};
        #pragma unroll
        for (int kt = 0; kt < 10; ++kt) {
            f16x8 bf[5];
            #pragma unroll
            for (int n = 0; n < 5; ++n)
                bf[n] = *(const f16x8*)(wb + (size_t)(n * 10 + kt) * 512);
            f16x8 af[2];
            #pragma unroll
            for (int mi = 0; mi < 2; ++mi)
                af[mi] = *(const f16x8*)(At + ((size_t)((mh * 2 + mi) * 10 + kt) * 64 + tx * 4 + quad) * 8);
            #pragma unroll
            for (int mi = 0; mi < 2; ++mi)
                #pragma unroll
                for (int n = 0; n < 5; ++n)
                    acc[mi][n] =
                        __builtin_amdgcn_mfma_f32_16x16x32_f16(af[mi], bf[n], acc[mi][n], 0, 0, 0);
        }

        // epilogue (register-only until part writes; loads can't be hoisted
        // across the in-loop atomic -> w3v/c2v don't stay live through MFMA)
        float w3v[5], c2v[5];
        #pragma unroll
        for (int n = 0; n < 5; ++n) {
            w3v[n] = w3p[colw + n * 16 + tx];
            c2v[n] = c2p[colw + n * 16 + tx];
        }
        #pragma unroll
        for (int mi = 0; mi < 2; ++mi) {
            float ps[4];
            if (p == 0) {
                ps[0] = ps[1] = ps[2] = ps[3] = 0.f;
                #pragma unroll
                for (int n = 0; n < 5; ++n)
                    #pragma unroll
                    for (int r = 0; r < 4; ++r)
                        ps[r] = fmaf(w3v[n], fmaxf(acc[mi][n][r], 0.f), ps[r]);
            } else {
                float prd[4] = {1.f, 1.f, 1.f, 1.f};
                #pragma unroll
                for (int n = 0; n < 5; ++n)
                    #pragma unroll
                    for (int r = 0; r < 4; ++r) {
                        const float hr = fmaxf(acc[mi][n][r], 0.f);
                        const float u  = __builtin_amdgcn_exp2f(c2v[n] * hr);  // e^{2a}
                        prd[r] *= fmaf(0.5f, u, 0.5f);
                    }
                #pragma unroll
                for (int r = 0; r < 4; ++r)
                    ps[r] = __builtin_amdgcn_logf(prd[r]);   // v_log_f32 = log2
            }
            #pragma unroll
            for (int r = 0; r < 4; ++r) {
                float v = ps[r];
                v += __shfl_xor(v, 1); v += __shfl_xor(v, 2);
                v += __shfl_xor(v, 4); v += __shfl_xor(v, 8);
                ps[r] = v;
            }
            if (tx == 0) {
                #pragma unroll
                for (int r = 0; r < 4; ++r)
                    part[(mh * 32 + mi * 16 + quad * 4 + r) * 4 + nq] = ps[r];
            }
        }
        __syncthreads();   // part ready (also: all MFMA At reads done)

        if (t < 64) {      // wave 0 only: fold 4 nq partials, reduce 64 rows
            const float4 pv = *(const float4*)(part + t * 4);
            const float s = pv.x + pv.y + pv.z + pv.w;
            float tot = (p == 0) ? s : __builtin_amdgcn_exp2f(s);
            tot += __shfl_xor(tot, 1);  tot += __shfl_xor(tot, 2);
            tot += __shfl_xor(tot, 4);  tot += __shfl_xor(tot, 8);
            tot += __shfl_xor(tot, 16); tot += __shfl_xor(tot, 32);
            if (t == 0) atomicAdd(&S[p], (double)tot);
        }
        // next iteration's At writes are safe: every wave's MFMA reads of At
        // precede the sync above; part(p+1) writes happen only after the
        // "At ready" sync of iteration p+1, which wave 0 reaches after its
        // part reads here.
    }
}

__global__ void fin_kernel(char* __restrict__ ws, float* __restrict__ out)
{
    if (threadIdx.x == 0 && blockIdx.x == 0) {
        const double* S = (const double*)(ws + OFF_S);
        double m1 = S[0] / (double)N_SAMP;
        double a = 0.0;
        for (int p = 1; p <= KPASS; ++p) a += log(S[p] / (double)N_SAMP);
        out[0] = (float)(m1 - a / (double)KPASS);
    }
}

extern "C" void kernel_launch(void* const* d_in, const int* in_sizes, int n_in,
                              void* d_out, int out_size, void* d_ws, size_t ws_size,
                              hipStream_t stream)
{
    const float* x  = (const float*)d_in[0];
    const int* ind  = (const int*)d_in[1];
    const float* W1 = (const float*)d_in[2];
    const float* b1 = (const float*)d_in[3];
    const float* W2 = (const float*)d_in[4];
    const float* b2 = (const float*)d_in[5];
    const float* W3 = (const float*)d_in[6];
    char* ws = (char*)d_ws;

    hipLaunchKernelGGL(prep_kernel, dim3(512), dim3(256), 0, stream, W1, b1, W2, b2, W3, ws);
    hipLaunchKernelGGL(fc1_kernel, dim3(N_SAMP / 128), dim3(256), 0, stream, x, ind, ws);
    hipLaunchKernelGGL(fc23_kernel, dim3(N_SAMP / 64), dim3(512), 0, stream, ws);
    hipLaunchKernelGGL(fin_kernel, dim3(1), dim3(64), 0, stream, ws, (float*)d_out);
}

// Round 2
// 1272.600 us; speedup vs baseline: 1.8521x; 1.8521x over previous
//
#include <hip/hip_runtime.h>
#include <hip/hip_fp16.h>

// MINE estimator, dropout analytically marginalized:
//   mean(z1)  -> no-dropout forward (exact expectation)
//   E[exp(z2)] = exp(b3) * prod_j (0.5 + 0.5*exp(2*a_j)),  a_j = w3_j*relu(h2_j)
//   permutation -> 20 fixed cyclic shifts (unbiased pairing estimator)
// R6: combine R4b's flat (2048,21) grid (TLP to hide stage latency) with R5's
//   8-wave 32x80 quadrant split (acc[2][5] = 40 regs). NOTHING held across
//   passes -> peak pressure ~110 < 128 cap of __launch_bounds__(512,4) ->
//   zero spill. P and Q both re-read per pass (both 84 MB, L3-resident;
//   registers are the scarce resource, not L3 bandwidth).
//   R5 post-mortem: loop-carried P-in-registers + bf/acc exceeded the cap;
//   spilled state was re-read 21x -> 5 GB of scratch FETCH, MfmaUtil 11%.

#define N_SAMP  131072
#define NMASK   (N_SAMP - 1)
#define HH      300
#define HPAD    320
#define DD      256
#define KPASS   20
#define PSTRIDE 320

#define OFF_S    ((size_t)0)
#define OFF_B1P  ((size_t)1024)
#define OFF_B2P  ((size_t)2304)
#define OFF_W3P  ((size_t)3584)
#define OFF_C2   ((size_t)4864)
#define OFF_W1B  ((size_t)8192)                       // [20 nt][8 kt][64 lane][8] f16
#define OFF_W2B  (OFF_W1B + (size_t)163840)           // [20 nt][10 kt][64 lane][8] f16
#define OFF_P    (OFF_W2B + (size_t)204800)
#define OFF_Q    (OFF_P + (size_t)N_SAMP*PSTRIDE*2)

typedef _Float16 f16x8 __attribute__((ext_vector_type(8)));
typedef float    fx4   __attribute__((ext_vector_type(4)));

__global__ void prep_kernel(const float* __restrict__ W1, const float* __restrict__ b1,
                            const float* __restrict__ W2, const float* __restrict__ b2,
                            const float* __restrict__ W3, char* __restrict__ ws)
{
    double* S     = (double*)(ws + OFF_S);
    float* b1p    = (float*)(ws + OFF_B1P);
    float* b2p    = (float*)(ws + OFF_B2P);
    float* w3p    = (float*)(ws + OFF_W3P);
    float* c2p    = (float*)(ws + OFF_C2);
    _Float16* w1b = (_Float16*)(ws + OFF_W1B);
    _Float16* w2b = (_Float16*)(ws + OFF_W2B);
    int tid = blockIdx.x * blockDim.x + threadIdx.x;
    int nth = gridDim.x * blockDim.x;
    if (tid <= KPASS) S[tid] = 0.0;
    for (int i = tid; i < HPAD; i += nth) {
        b1p[i] = (i < HH) ? b1[i] : 0.f;
        b2p[i] = (i < HH) ? b2[i] : 0.f;
        w3p[i] = (i < HH) ? W3[i] : 0.f;
        c2p[i] = (i < HH) ? 2.8853900817779268f * W3[i] : 0.f;  // 2*log2(e)*w3
    }
    // w1b: frag (nt,kt): value = W1[n][k], n = nt*16+tx, k = kt*32+quad*8+j (K=256)
    for (int i = tid; i < 20 * 8 * 64 * 8; i += nth) {
        const int j = i & 7, lane = (i >> 3) & 63, rem = i >> 9;
        const int kt = rem & 7, nt = rem >> 3;
        const int n = nt * 16 + (lane & 15);
        const int k = kt * 32 + (lane >> 4) * 8 + j;
        w1b[i] = (n < HH) ? (_Float16)W1[n * DD + k] : (_Float16)0.f;
    }
    // w2b: frag (nt,kt): value = W2[n][k]; row k==300 carries b2 (bias fold)
    for (int i = tid; i < 20 * 10 * 64 * 8; i += nth) {
        const int j = i & 7, lane = (i >> 3) & 63, rem = i >> 9;
        const int kt = rem % 10, nt = rem / 10;
        const int n = nt * 16 + (lane & 15);
        const int k = kt * 32 + (lane >> 4) * 8 + j;
        float v = 0.f;
        if (n < HH) {
            if (k < HH)       v = W2[n * HH + k];
            else if (k == HH) v = b2[n];
        }
        w2b[i] = (_Float16)v;
    }
}

// fc1 on MFMA: gather x rows -> fp16 A-frags in LDS; P = u*W1a^T + b1 (kt 0..3),
// Q = v*W1b^T (kt 4..7). Epilogue transposes through LDS for coalesced stores.
__global__ __launch_bounds__(256, 2)
void fc1_kernel(const float* __restrict__ x, const int* __restrict__ ind,
                char* __restrict__ ws)
{
    const _Float16* w1b = (const _Float16*)(ws + OFF_W1B);
    const float* b1p    = (const float*)(ws + OFF_B1P);
    const int i0 = blockIdx.x * 128;

    __shared__ __align__(16) char lds[65536];   // At [8 kt][8 mt][64 slot][8] f16
    _Float16* At  = (_Float16*)lds;
    _Float16* buf = (_Float16*)lds;

    const int t    = threadIdx.x;
    const int lane = t & 63, w = t >> 6;
    const int tx   = lane & 15, quad = lane >> 4;
    const int colw = w * 80;

    {
        const int m = t >> 1, c = t & 1;
        const int mt = m >> 4, ml = m & 15;
        const int r = ind[i0 + m];
        const float* xr = x + (size_t)r * DD;
        #pragma unroll
        for (int i = 0; i < 16; ++i) {
            const int ch = 2 * i + c;
            const int kt = ch >> 2, qd = ch & 3;
            const float4 f0 = *(const float4*)(xr + ch * 8);
            const float4 f1 = *(const float4*)(xr + ch * 8 + 4);
            f16x8 h;
            h[0] = (_Float16)f0.x; h[1] = (_Float16)f0.y;
            h[2] = (_Float16)f0.z; h[3] = (_Float16)f0.w;
            h[4] = (_Float16)f1.x; h[5] = (_Float16)f1.y;
            h[6] = (_Float16)f1.z; h[7] = (_Float16)f1.w;
            *(f16x8*)(At + ((size_t)(kt * 8 + mt) * 64 + ml * 4 + qd) * 8) = h;
        }
    }
    __syncthreads();

    #pragma unroll
    for (int ph = 0; ph < 2; ++ph) {
        fx4 acc[8][5] = {};
        #pragma unroll
        for (int kt = 0; kt < 4; ++kt) {
            const int ktg = ph * 4 + kt;
            f16x8 bf[5];
            #pragma unroll
            for (int n = 0; n < 5; ++n)
                bf[n] = *(const f16x8*)(w1b + ((size_t)((w * 5 + n) * 8 + ktg) * 64 + lane) * 8);
            #pragma unroll
            for (int mh = 0; mh < 2; ++mh) {
                f16x8 af[4];
                #pragma unroll
                for (int mi = 0; mi < 4; ++mi)
                    af[mi] = *(const f16x8*)(At + ((size_t)(ktg * 8 + mh * 4 + mi) * 64 + tx * 4 + quad) * 8);
                #pragma unroll
                for (int mi = 0; mi < 4; ++mi)
                    #pragma unroll
                    for (int n = 0; n < 5; ++n)
                        acc[mh * 4 + mi][n] =
                            __builtin_amdgcn_mfma_f32_16x16x32_f16(af[mi], bf[n], acc[mh * 4 + mi][n], 0, 0, 0);
            }
        }
        _Float16* out = (_Float16*)(ws + (ph ? OFF_Q : OFF_P));
        #pragma unroll
        for (int g = 0; g < 4; ++g) {
            __syncthreads();
            #pragma unroll
            for (int mi = 0; mi < 2; ++mi) {
                const int mt = g * 2 + mi;
                #pragma unroll
                for (int n = 0; n < 5; ++n) {
                    const int col = colw + n * 16 + tx;
                    const float bb = (ph == 0) ? b1p[col] : 0.f;
                    #pragma unroll
                    for (int r = 0; r < 4; ++r) {
                        const int row32 = mi * 16 + quad * 4 + r;
                        buf[row32 * 328 + col] = (_Float16)(acc[mt][n][r] + bb);
                    }
                }
            }
            __syncthreads();
            #pragma unroll
            for (int s5 = 0; s5 < 5; ++s5) {
                const int idx = t + s5 * 256;
                const int rr = idx / 40, cc = idx - rr * 40;
                *(uint4*)(out + (size_t)(i0 + g * 32 + rr) * PSTRIDE + cc * 8) =
                    *(const uint4*)(buf + rr * 328 + cc * 8);
            }
        }
        __syncthreads();
    }
}

// fc2+fc3: h1 = relu(P_i + Q_{(i+shift)&mask}) [col 300 = 1 -> b2 fold];
// h2 = h1*W2b^T; epilogue in exp2/log2 domain.
// R6: grid (2048, 21); 512 threads / 8 waves as (mh 0..1) x (nq 0..3);
// each wave owns 32 rows x 80 cols -> acc[2][5]. P and Q re-read per pass
// (L3-resident). B-frags double-buffered. No loop-carried register state.
__global__ __launch_bounds__(512, 4)
void fc23_kernel(char* __restrict__ ws)
{
    const _Float16* w2b = (const _Float16*)(ws + OFF_W2B);
    const float* w3p = (const float*)(ws + OFF_W3P);
    const float* c2p = (const float*)(ws + OFF_C2);
    const _Float16* P = (const _Float16*)(ws + OFF_P);
    const _Float16* Q = (const _Float16*)(ws + OFF_Q);
    double* S = (double*)(ws + OFF_S);

    const int p  = blockIdx.y;
    const int i0 = blockIdx.x * 64;
    const unsigned shift = (p == 0) ? 0u : (((unsigned)p * 2654435761u) & NMASK);

    __shared__ __align__(16) char lds[40960 + 1024];
    _Float16* At = (_Float16*)lds;              // [4 mt][10 kt][64 slot][8] f16
    float* part = (float*)(lds + 40960);        // [64 rows][4 nq]

    const int t    = threadIdx.x;
    const int lane = t & 63, w = t >> 6;
    const int tx   = lane & 15, quad = lane >> 4;
    const int mh   = w >> 2, nq = w & 3;
    const int colw = nq * 80;

    // B-frag base for this wave's nq quadrant; prefetch kt=0 before staging
    const _Float16* wb = w2b + (size_t)(nq * 5) * 10 * 512 + (size_t)lane * 8;
    f16x8 bA[5], bB[5];
    #pragma unroll
    for (int n = 0; n < 5; ++n) bA[n] = *(const f16x8*)(wb + (size_t)(n * 10) * 512);

    { // stage h1 = relu(P+Q): 8 threads/row, 5 chunks each (ch = sc + 8i)
        const int sc = t & 7, sm = t >> 3;
        const int smt = sm >> 4, sml = sm & 15;
        const int prow = i0 + sm;
        const _Float16* pr = P + (size_t)prow * PSTRIDE;
        const _Float16* qr = Q + (size_t)(((unsigned)prow + shift) & NMASK) * PSTRIDE;
        #pragma unroll
        for (int i = 0; i < 5; ++i) {
            const int ch = sc + 8 * i;
            f16x8 hp = *(const f16x8*)(pr + ch * 8);
            f16x8 hq = *(const f16x8*)(qr + ch * 8);
            f16x8 sv = hp + hq;
            sv = __builtin_elementwise_max(sv, (f16x8)(_Float16)0);
            if (ch == 37) sv[4] = (_Float16)1.f;   // k=300: bias column
            const int kt = ch >> 2, cq = ch & 3;
            *(f16x8*)(At + ((size_t)(smt * 10 + kt) * 64 + sml * 4 + cq) * 8) = sv;
        }
    }
    __syncthreads();

    fx4 acc[2][5] = {};
    #pragma unroll
    for (int kt = 0; kt < 10; ++kt) {
        f16x8* bc = (kt & 1) ? bB : bA;
        f16x8* bn = (kt & 1) ? bA : bB;
        if (kt < 9) {
            #pragma unroll
            for (int n = 0; n < 5; ++n)
                bn[n] = *(const f16x8*)(wb + (size_t)(n * 10 + kt + 1) * 512);
        }
        f16x8 af[2];
        #pragma unroll
        for (int mi = 0; mi < 2; ++mi)
            af[mi] = *(const f16x8*)(At + ((size_t)((mh * 2 + mi) * 10 + kt) * 64 + tx * 4 + quad) * 8);
        #pragma unroll
        for (int mi = 0; mi < 2; ++mi)
            #pragma unroll
            for (int n = 0; n < 5; ++n)
                acc[mi][n] =
                    __builtin_amdgcn_mfma_f32_16x16x32_f16(af[mi], bc[n], acc[mi][n], 0, 0, 0);
    }

    // epilogue: fc3 dot (p==0) or marginalized-dropout product (p>0),
    // in exp2/log2 domain with one log per 20-element product
    float w3v[5], c2v[5];
    #pragma unroll
    for (int n = 0; n < 5; ++n) {
        w3v[n] = w3p[colw + n * 16 + tx];
        c2v[n] = c2p[colw + n * 16 + tx];
    }
    #pragma unroll
    for (int mi = 0; mi < 2; ++mi) {
        float ps[4];
        if (p == 0) {
            ps[0] = ps[1] = ps[2] = ps[3] = 0.f;
            #pragma unroll
            for (int n = 0; n < 5; ++n)
                #pragma unroll
                for (int r = 0; r < 4; ++r)
                    ps[r] = fmaf(w3v[n], fmaxf(acc[mi][n][r], 0.f), ps[r]);
        } else {
            float prd[4] = {1.f, 1.f, 1.f, 1.f};
            #pragma unroll
            for (int n = 0; n < 5; ++n)
                #pragma unroll
                for (int r = 0; r < 4; ++r) {
                    const float hr = fmaxf(acc[mi][n][r], 0.f);
                    const float u  = __builtin_amdgcn_exp2f(c2v[n] * hr);  // e^{2a}
                    prd[r] *= fmaf(0.5f, u, 0.5f);
                }
            #pragma unroll
            for (int r = 0; r < 4; ++r)
                ps[r] = __builtin_amdgcn_logf(prd[r]);   // v_log_f32 = log2
        }
        #pragma unroll
        for (int r = 0; r < 4; ++r) {
            float v = ps[r];
            v += __shfl_xor(v, 1); v += __shfl_xor(v, 2);
            v += __shfl_xor(v, 4); v += __shfl_xor(v, 8);
            ps[r] = v;
        }
        if (tx == 0) {
            #pragma unroll
            for (int r = 0; r < 4; ++r)
                part[(mh * 32 + mi * 16 + quad * 4 + r) * 4 + nq] = ps[r];
        }
    }
    __syncthreads();

    if (t < 64) {      // wave 0: fold 4 nq partials, reduce 64 rows
        const float4 pv = *(const float4*)(part + t * 4);
        const float s = pv.x + pv.y + pv.z + pv.w;
        float tot = (p == 0) ? s : __builtin_amdgcn_exp2f(s);
        tot += __shfl_xor(tot, 1);  tot += __shfl_xor(tot, 2);
        tot += __shfl_xor(tot, 4);  tot += __shfl_xor(tot, 8);
        tot += __shfl_xor(tot, 16); tot += __shfl_xor(tot, 32);
        if (t == 0) atomicAdd(&S[p], (double)tot);
    }
}

__global__ void fin_kernel(char* __restrict__ ws, float* __restrict__ out)
{
    if (threadIdx.x == 0 && blockIdx.x == 0) {
        const double* S = (const double*)(ws + OFF_S);
        double m1 = S[0] / (double)N_SAMP;
        double a = 0.0;
        for (int p = 1; p <= KPASS; ++p) a += log(S[p] / (double)N_SAMP);
        out[0] = (float)(m1 - a / (double)KPASS);
    }
}

extern "C" void kernel_launch(void* const* d_in, const int* in_sizes, int n_in,
                              void* d_out, int out_size, void* d_ws, size_t ws_size,
                              hipStream_t stream)
{
    const float* x  = (const float*)d_in[0];
    const int* ind  = (const int*)d_in[1];
    const float* W1 = (const float*)d_in[2];
    const float* b1 = (const float*)d_in[3];
    const float* W2 = (const float*)d_in[4];
    const float* b2 = (const float*)d_in[5];
    const float* W3 = (const float*)d_in[6];
    char* ws = (char*)d_ws;

    hipLaunchKernelGGL(prep_kernel, dim3(512), dim3(256), 0, stream, W1, b1, W2, b2, W3, ws);
    hipLaunchKernelGGL(fc1_kernel, dim3(N_SAMP / 128), dim3(256), 0, stream, x, ind, ws);
    hipLaunchKernelGGL(fc23_kernel, dim3(N_SAMP / 64, KPASS + 1), dim3(512), 0, stream, ws);
    hipLaunchKernelGGL(fin_kernel, dim3(1), dim3(64), 0, stream, ws, (float*)d_out);
}

// Round 3
// 1117.940 us; speedup vs baseline: 2.1083x; 1.1383x over previous
//
#include <hip/hip_runtime.h>
#include <hip/hip_fp16.h>

// MINE estimator, dropout analytically marginalized:
//   mean(z1)  -> no-dropout forward (exact expectation)
//   E[exp(z2)] = exp(b3) * prod_j (0.5 + 0.5*exp(2*a_j)),  a_j = w3_j*relu(h2_j)
//   permutation -> 20 fixed cyclic shifts (unbiased pairing estimator)
// R7: latency attack. R6 was latency-bound (MfmaUtil 25 / VALU 36 / HBM 22 /
//   Occ 40 -- everything idle): 10 MFMAs per kt (~48cy) can't hide the 5
//   B-frag load latency, and occupancy is register-capped (96 regs -> 5 w/SIMD).
//   - fc23 back to 4 waves x acc[4][5] (20 MFMAs/kt ~= 97cy of issue per 5
//     loads -> ILP covers L1 latency). Spill avoided via launch_bounds(256,3):
//     cap 170 regs; need ~156 (80 AGPR acc + 40 bf + 16 af + misc). R4b's
//     spill came from (256,4)'s 128 cap, not from the tiling.
//   - At slot XOR-swizzle (s ^= (s>>3)&3): af ds_read_b128 was a 4-way bank
//     conflict (lanes 0-7 hit 2 of 8 bank-quads; SQ_LDS_BANK_CONFLICT 4.13e7
//     matches 6.9e6 reads x ~6cy). Slot is per-thread constant -> swizzle is
//     free. Write side stays <=2-way (free).
//   - w2b reordered kt-major [nq][kt*5+n][lane][8]: B-frags stream at 1KB
//     stride -> one induction pointer + imm offsets (cuts ~100 addr-VALU per
//     thread-pass), and the mh/nq-sharing makes the stream L1-resident.

#define N_SAMP  131072
#define NMASK   (N_SAMP - 1)
#define HH      300
#define HPAD    320
#define DD      256
#define KPASS   20
#define PSTRIDE 320

#define OFF_S    ((size_t)0)
#define OFF_B1P  ((size_t)1024)
#define OFF_B2P  ((size_t)2304)
#define OFF_W3P  ((size_t)3584)
#define OFF_C2   ((size_t)4864)
#define OFF_W1B  ((size_t)8192)                       // [20 nt][8 kt][64 lane][8] f16
#define OFF_W2B  (OFF_W1B + (size_t)163840)           // [4 nq][50 ktn][64 lane][8] f16
#define OFF_P    (OFF_W2B + (size_t)204800)
#define OFF_Q    (OFF_P + (size_t)N_SAMP*PSTRIDE*2)

typedef _Float16 f16x8 __attribute__((ext_vector_type(8)));
typedef float    fx4   __attribute__((ext_vector_type(4)));

__global__ void prep_kernel(const float* __restrict__ W1, const float* __restrict__ b1,
                            const float* __restrict__ W2, const float* __restrict__ b2,
                            const float* __restrict__ W3, char* __restrict__ ws)
{
    double* S     = (double*)(ws + OFF_S);
    float* b1p    = (float*)(ws + OFF_B1P);
    float* b2p    = (float*)(ws + OFF_B2P);
    float* w3p    = (float*)(ws + OFF_W3P);
    float* c2p    = (float*)(ws + OFF_C2);
    _Float16* w1b = (_Float16*)(ws + OFF_W1B);
    _Float16* w2b = (_Float16*)(ws + OFF_W2B);
    int tid = blockIdx.x * blockDim.x + threadIdx.x;
    int nth = gridDim.x * blockDim.x;
    if (tid <= KPASS) S[tid] = 0.0;
    for (int i = tid; i < HPAD; i += nth) {
        b1p[i] = (i < HH) ? b1[i] : 0.f;
        b2p[i] = (i < HH) ? b2[i] : 0.f;
        w3p[i] = (i < HH) ? W3[i] : 0.f;
        c2p[i] = (i < HH) ? 2.8853900817779268f * W3[i] : 0.f;  // 2*log2(e)*w3
    }
    // w1b: frag (nt,kt): value = W1[n][k], n = nt*16+tx, k = kt*32+quad*8+j (K=256)
    for (int i = tid; i < 20 * 8 * 64 * 8; i += nth) {
        const int j = i & 7, lane = (i >> 3) & 63, rem = i >> 9;
        const int kt = rem & 7, nt = rem >> 3;
        const int n = nt * 16 + (lane & 15);
        const int k = kt * 32 + (lane >> 4) * 8 + j;
        w1b[i] = (n < HH) ? (_Float16)W1[n * DD + k] : (_Float16)0.f;
    }
    // w2b kt-major: [nq][kt*5+n][lane][8]; value = W2[nt*16+tx][kt*32+quad*8+j],
    // nt = nq*5+n; row k==300 carries b2 (bias fold)
    for (int i = tid; i < 4 * 50 * 64 * 8; i += nth) {
        const int j = i & 7, lane = (i >> 3) & 63, rem = i >> 9;   // rem 0..199
        const int nq = rem / 50, r2 = rem - nq * 50;
        const int kt = r2 / 5,  nn = r2 - kt * 5;
        const int nt = nq * 5 + nn;
        const int n = nt * 16 + (lane & 15);
        const int k = kt * 32 + (lane >> 4) * 8 + j;
        float v = 0.f;
        if (n < HH) {
            if (k < HH)       v = W2[n * HH + k];
            else if (k == HH) v = b2[n];
        }
        w2b[i] = (_Float16)v;
    }
}

// fc1 on MFMA: gather x rows -> fp16 A-frags in LDS; P = u*W1a^T + b1 (kt 0..3),
// Q = v*W1b^T (kt 4..7). Epilogue transposes through LDS for coalesced stores.
__global__ __launch_bounds__(256, 2)
void fc1_kernel(const float* __restrict__ x, const int* __restrict__ ind,
                char* __restrict__ ws)
{
    const _Float16* w1b = (const _Float16*)(ws + OFF_W1B);
    const float* b1p    = (const float*)(ws + OFF_B1P);
    const int i0 = blockIdx.x * 128;

    __shared__ __align__(16) char lds[65536];   // At [8 kt][8 mt][64 slot][8] f16
    _Float16* At  = (_Float16*)lds;
    _Float16* buf = (_Float16*)lds;

    const int t    = threadIdx.x;
    const int lane = t & 63, w = t >> 6;
    const int tx   = lane & 15, quad = lane >> 4;
    const int colw = w * 80;

    {
        const int m = t >> 1, c = t & 1;
        const int mt = m >> 4, ml = m & 15;
        const int r = ind[i0 + m];
        const float* xr = x + (size_t)r * DD;
        #pragma unroll
        for (int i = 0; i < 16; ++i) {
            const int ch = 2 * i + c;
            const int kt = ch >> 2, qd = ch & 3;
            const float4 f0 = *(const float4*)(xr + ch * 8);
            const float4 f1 = *(const float4*)(xr + ch * 8 + 4);
            f16x8 h;
            h[0] = (_Float16)f0.x; h[1] = (_Float16)f0.y;
            h[2] = (_Float16)f0.z; h[3] = (_Float16)f0.w;
            h[4] = (_Float16)f1.x; h[5] = (_Float16)f1.y;
            h[6] = (_Float16)f1.z; h[7] = (_Float16)f1.w;
            *(f16x8*)(At + ((size_t)(kt * 8 + mt) * 64 + ml * 4 + qd) * 8) = h;
        }
    }
    __syncthreads();

    #pragma unroll
    for (int ph = 0; ph < 2; ++ph) {
        fx4 acc[8][5] = {};
        #pragma unroll
        for (int kt = 0; kt < 4; ++kt) {
            const int ktg = ph * 4 + kt;
            f16x8 bf[5];
            #pragma unroll
            for (int n = 0; n < 5; ++n)
                bf[n] = *(const f16x8*)(w1b + ((size_t)((w * 5 + n) * 8 + ktg) * 64 + lane) * 8);
            #pragma unroll
            for (int mh = 0; mh < 2; ++mh) {
                f16x8 af[4];
                #pragma unroll
                for (int mi = 0; mi < 4; ++mi)
                    af[mi] = *(const f16x8*)(At + ((size_t)(ktg * 8 + mh * 4 + mi) * 64 + tx * 4 + quad) * 8);
                #pragma unroll
                for (int mi = 0; mi < 4; ++mi)
                    #pragma unroll
                    for (int n = 0; n < 5; ++n)
                        acc[mh * 4 + mi][n] =
                            __builtin_amdgcn_mfma_f32_16x16x32_f16(af[mi], bf[n], acc[mh * 4 + mi][n], 0, 0, 0);
            }
        }
        _Float16* out = (_Float16*)(ws + (ph ? OFF_Q : OFF_P));
        #pragma unroll
        for (int g = 0; g < 4; ++g) {
            __syncthreads();
            #pragma unroll
            for (int mi = 0; mi < 2; ++mi) {
                const int mt = g * 2 + mi;
                #pragma unroll
                for (int n = 0; n < 5; ++n) {
                    const int col = colw + n * 16 + tx;
                    const float bb = (ph == 0) ? b1p[col] : 0.f;
                    #pragma unroll
                    for (int r = 0; r < 4; ++r) {
                        const int row32 = mi * 16 + quad * 4 + r;
                        buf[row32 * 328 + col] = (_Float16)(acc[mt][n][r] + bb);
                    }
                }
            }
            __syncthreads();
            #pragma unroll
            for (int s5 = 0; s5 < 5; ++s5) {
                const int idx = t + s5 * 256;
                const int rr = idx / 40, cc = idx - rr * 40;
                *(uint4*)(out + (size_t)(i0 + g * 32 + rr) * PSTRIDE + cc * 8) =
                    *(const uint4*)(buf + rr * 328 + cc * 8);
            }
        }
        __syncthreads();
    }
}

// fc2+fc3: h1 = relu(P_i + Q_{(i+shift)&mask}) [col 300 = 1 -> b2 fold];
// h2 = h1*W2b^T; epilogue in exp2/log2 domain.
// R7: grid (2048, 21); 256 threads / 4 waves, each wave owns 64 rows x 80
// cols (acc[4][5] in AGPRs). 20 MFMAs per kt hide the 5 B-frag loads.
// At slots XOR-swizzled; w2b streamed kt-major.
__global__ __launch_bounds__(256, 3)
void fc23_kernel(char* __restrict__ ws)
{
    const _Float16* w2b = (const _Float16*)(ws + OFF_W2B);
    const float* w3p = (const float*)(ws + OFF_W3P);
    const float* c2p = (const float*)(ws + OFF_C2);
    const _Float16* P = (const _Float16*)(ws + OFF_P);
    const _Float16* Q = (const _Float16*)(ws + OFF_Q);
    double* S = (double*)(ws + OFF_S);

    const int p  = blockIdx.y;
    const int i0 = blockIdx.x * 64;
    const unsigned shift = (p == 0) ? 0u : (((unsigned)p * 2654435761u) & NMASK);

    __shared__ __align__(16) char lds[40960 + 1024];
    _Float16* At = (_Float16*)lds;              // [4 mt][10 kt][64 slot^swz][8] f16
    float* part = (float*)(lds + 40960);        // [64 rows][4 waves]

    const int t    = threadIdx.x;
    const int lane = t & 63, w = t >> 6;        // w = nq quadrant, 0..3
    const int tx   = lane & 15, quad = lane >> 4;
    const int colw = w * 80;

    // B-frag stream base (kt-major): frag (kt,n) at +(kt*5+n)*512 f16
    const _Float16* wb = w2b + (size_t)(w * 50) * 512 + (size_t)lane * 8;
    f16x8 bA[5], bB[5];
    #pragma unroll
    for (int n = 0; n < 5; ++n) bA[n] = *(const f16x8*)(wb + (size_t)n * 512);

    { // stage h1 = relu(P+Q): 4 threads/row, 10 chunks each (ch = c + 4i; kt = i)
        const int c = t & 3, m = t >> 2;
        const int mt = m >> 4, ml = m & 15;
        const int prow = i0 + m;
        int ws_ = ml * 4 + c;  ws_ ^= (ws_ >> 3) & 3;       // swizzled write slot
        const _Float16* pr = P + (size_t)prow * PSTRIDE;
        const _Float16* qr = Q + (size_t)(((unsigned)prow + shift) & NMASK) * PSTRIDE;
        #pragma unroll
        for (int i = 0; i < 10; ++i) {
            const int ch = c + 4 * i;                        // kt = i, cq = c
            f16x8 hp = *(const f16x8*)(pr + ch * 8);
            f16x8 hq = *(const f16x8*)(qr + ch * 8);
            f16x8 sv = hp + hq;
            sv = __builtin_elementwise_max(sv, (f16x8)(_Float16)0);
            if (i == 9 && c == 1) sv[4] = (_Float16)1.f;     // ch=37, k=300: bias col
            *(f16x8*)(At + ((size_t)(mt * 10 + i) * 64 + ws_) * 8) = sv;
        }
    }
    __syncthreads();

    int rs = tx * 4 + quad;  rs ^= (rs >> 3) & 3;            // swizzled read slot

    fx4 acc[4][5] = {};
    #pragma unroll
    for (int kt = 0; kt < 10; ++kt) {
        f16x8* bc = (kt & 1) ? bB : bA;
        f16x8* bn = (kt & 1) ? bA : bB;
        if (kt < 9) {
            #pragma unroll
            for (int n = 0; n < 5; ++n)
                bn[n] = *(const f16x8*)(wb + (size_t)((kt + 1) * 5 + n) * 512);
        }
        f16x8 af[4];
        #pragma unroll
        for (int mi = 0; mi < 4; ++mi)
            af[mi] = *(const f16x8*)(At + ((size_t)(mi * 10 + kt) * 64 + rs) * 8);
        #pragma unroll
        for (int mi = 0; mi < 4; ++mi)
            #pragma unroll
            for (int n = 0; n < 5; ++n)
                acc[mi][n] =
                    __builtin_amdgcn_mfma_f32_16x16x32_f16(af[mi], bc[n], acc[mi][n], 0, 0, 0);
    }

    // epilogue: fc3 dot (p==0) or marginalized-dropout product (p>0),
    // in exp2/log2 domain with one log per 20-element product
    float w3v[5], c2v[5];
    #pragma unroll
    for (int n = 0; n < 5; ++n) {
        w3v[n] = w3p[colw + n * 16 + tx];
        c2v[n] = c2p[colw + n * 16 + tx];
    }
    #pragma unroll
    for (int mi = 0; mi < 4; ++mi) {
        float ps[4];
        if (p == 0) {
            ps[0] = ps[1] = ps[2] = ps[3] = 0.f;
            #pragma unroll
            for (int n = 0; n < 5; ++n)
                #pragma unroll
                for (int r = 0; r < 4; ++r)
                    ps[r] = fmaf(w3v[n], fmaxf(acc[mi][n][r], 0.f), ps[r]);
        } else {
            float prd[4] = {1.f, 1.f, 1.f, 1.f};
            #pragma unroll
            for (int n = 0; n < 5; ++n)
                #pragma unroll
                for (int r = 0; r < 4; ++r) {
                    const float hr = fmaxf(acc[mi][n][r], 0.f);
                    const float u  = __builtin_amdgcn_exp2f(c2v[n] * hr);  // e^{2a}
                    prd[r] *= fmaf(0.5f, u, 0.5f);
                }
            #pragma unroll
            for (int r = 0; r < 4; ++r)
                ps[r] = __builtin_amdgcn_logf(prd[r]);   // v_log_f32 = log2
        }
        #pragma unroll
        for (int r = 0; r < 4; ++r) {
            float v = ps[r];
            v += __shfl_xor(v, 1); v += __shfl_xor(v, 2);
            v += __shfl_xor(v, 4); v += __shfl_xor(v, 8);
            ps[r] = v;
        }
        if (tx == 0) {
            #pragma unroll
            for (int r = 0; r < 4; ++r)
                part[(mi * 16 + quad * 4 + r) * 4 + w] = ps[r];
        }
    }
    __syncthreads();

    if (t < 64) {      // wave 0: fold 4 nq partials, reduce 64 rows
        const float4 pv = *(const float4*)(part + t * 4);
        const float s = pv.x + pv.y + pv.z + pv.w;
        float tot = (p == 0) ? s : __builtin_amdgcn_exp2f(s);
        tot += __shfl_xor(tot, 1);  tot += __shfl_xor(tot, 2);
        tot += __shfl_xor(tot, 4);  tot += __shfl_xor(tot, 8);
        tot += __shfl_xor(tot, 16); tot += __shfl_xor(tot, 32);
        if (t == 0) atomicAdd(&S[p], (double)tot);
    }
}

__global__ void fin_kernel(char* __restrict__ ws, float* __restrict__ out)
{
    if (threadIdx.x == 0 && blockIdx.x == 0) {
        const double* S = (const double*)(ws + OFF_S);
        double m1 = S[0] / (double)N_SAMP;
        double a = 0.0;
        for (int p = 1; p <= KPASS; ++p) a += log(S[p] / (double)N_SAMP);
        out[0] = (float)(m1 - a / (double)KPASS);
    }
}

extern "C" void kernel_launch(void* const* d_in, const int* in_sizes, int n_in,
                              void* d_out, int out_size, void* d_ws, size_t ws_size,
                              hipStream_t stream)
{
    const float* x  = (const float*)d_in[0];
    const int* ind  = (const int*)d_in[1];
    const float* W1 = (const float*)d_in[2];
    const float* b1 = (const float*)d_in[3];
    const float* W2 = (const float*)d_in[4];
    const float* b2 = (const float*)d_in[5];
    const float* W3 = (const float*)d_in[6];
    char* ws = (char*)d_ws;

    hipLaunchKernelGGL(prep_kernel, dim3(512), dim3(256), 0, stream, W1, b1, W2, b2, W3, ws);
    hipLaunchKernelGGL(fc1_kernel, dim3(N_SAMP / 128), dim3(256), 0, stream, x, ind, ws);
    hipLaunchKernelGGL(fc23_kernel, dim3(N_SAMP / 64, KPASS + 1), dim3(256), 0, stream, ws);
    hipLaunchKernelGGL(fin_kernel, dim3(1), dim3(64), 0, stream, ws, (float*)d_out);
}